// Round 2
// baseline (73.408 us; speedup 1.0000x reference)
//
#include <hip/hip_runtime.h>
#include <hip/hip_bf16.h>
#include <float.h>

#define EPSV 1e-6f
#define TILE 1024     // targets staged per LDS tile (float4 each = 16 KB)
#define NCHUNK 4      // waves per block; wave w handles targets i % 4 == w

// Directed Hausdorff (squared), expansion form:
//   |s'-t|^2 = |s'|^2 + (|t|^2 - 2 s'.t),   s' = s + eps
// Block covers 64 src points x 4 target-chunks (one chunk per wave).
// Per-src min combined across waves in LDS, then block max -> atomicMax(ws[b]).
// grid: x = ceil(Lmax/64), y = batch, z = direction.
__global__ __launch_bounds__(256, 4) void hausdorff_directed_kernel(
    const float* __restrict__ c1, const float* __restrict__ c2,
    unsigned int* __restrict__ ws, int L1, int L2) {

    const int b   = blockIdx.y;
    const int dir = blockIdx.z;

    const float* src; const float* tgt; int Lsrc, Ltgt;
    if (dir == 0) { src = c2 + (size_t)b * L2 * 2; tgt = c1 + (size_t)b * L1 * 2; Lsrc = L2; Ltgt = L1; }
    else          { src = c1 + (size_t)b * L1 * 2; tgt = c2 + (size_t)b * L2 * 2; Lsrc = L1; Ltgt = L2; }

    if (blockIdx.x * 64 >= Lsrc) return;   // uniform across block

    const int lane = threadIdx.x & 63;
    const int w    = threadIdx.x >> 6;
    const int j    = blockIdx.x * 64 + lane;
    const bool active = (j < Lsrc);

    __shared__ float4 t_lds[TILE];
    __shared__ float  red[NCHUNK * 64];

    float nsx = 0.f, nsy = 0.f, s2 = 0.f;
    if (active) {
        float2 s = ((const float2*)src)[j];
        float sx = s.x + EPSV, sy = s.y + EPSV;
        nsx = -2.0f * sx;
        nsy = -2.0f * sy;
        s2  = fmaf(sx, sx, sy * sy);
    }

    float m0 = FLT_MAX, m1 = FLT_MAX, m2 = FLT_MAX, m3 = FLT_MAX;

    for (int base = 0; base < Ltgt; base += TILE) {
        const int chunk = min(TILE, Ltgt - base);
        // cooperative, coalesced stage: (tx, ty, |t|^2)
        for (int t = threadIdx.x; t < chunk; t += 256) {
            float2 p = ((const float2*)tgt)[base + t];
            t_lds[t] = make_float4(p.x, p.y, fmaf(p.x, p.x, p.y * p.y), 0.f);
        }
        __syncthreads();

        // wave w processes i = 4k + w  (uniform LDS address per wave -> broadcast)
        const int nk  = (chunk - w + NCHUNK - 1) >> 2;   // #k with 4k+w < chunk
        const int lim = nk & ~3;
        int k = 0;
        for (; k < lim; k += 4) {
            float4 a0 = t_lds[((k + 0) << 2) | w];
            float4 a1 = t_lds[((k + 1) << 2) | w];
            float4 a2 = t_lds[((k + 2) << 2) | w];
            float4 a3 = t_lds[((k + 3) << 2) | w];
            float d0 = fmaf(a0.x, nsx, fmaf(a0.y, nsy, a0.z));
            float d1 = fmaf(a1.x, nsx, fmaf(a1.y, nsy, a1.z));
            float d2 = fmaf(a2.x, nsx, fmaf(a2.y, nsy, a2.z));
            float d3 = fmaf(a3.x, nsx, fmaf(a3.y, nsy, a3.z));
            m0 = fminf(m0, d0);
            m1 = fminf(m1, d1);
            m2 = fminf(m2, d2);
            m3 = fminf(m3, d3);
        }
        for (; k < nk; ++k) {
            float4 a0 = t_lds[(k << 2) | w];
            m0 = fminf(m0, fmaf(a0.x, nsx, fmaf(a0.y, nsy, a0.z)));
        }
        __syncthreads();
    }

    // per-src partial min across the 4 waves
    red[threadIdx.x] = fminf(fminf(m0, m1), fminf(m2, m3));
    __syncthreads();

    if (w == 0) {
        float m = fminf(fminf(red[lane], red[64 + lane]),
                        fminf(red[128 + lane], red[192 + lane]));
        float v = fmaxf(s2 + m, 0.0f);   // clamp rounding-negative before uint ordering
        if (!active) v = 0.0f;
        for (int off = 32; off > 0; off >>= 1)
            v = fmaxf(v, __shfl_down(v, off));
        if (lane == 0) atomicMax(&ws[b], __float_as_uint(v));
    }
}

__global__ void hausdorff_finalize_kernel(const unsigned int* __restrict__ ws,
                                          const float* __restrict__ res,
                                          float* __restrict__ out, int B) {
    int t = threadIdx.x;
    if (t < B) {
        out[t] = sqrtf(__uint_as_float(ws[t])) * res[t];
    }
}

extern "C" void kernel_launch(void* const* d_in, const int* in_sizes, int n_in,
                              void* d_out, int out_size, void* d_ws, size_t ws_size,
                              hipStream_t stream) {
    const float* c1  = (const float*)d_in[0];
    const float* c2  = (const float*)d_in[1];
    const float* res = (const float*)d_in[2];
    float* out = (float*)d_out;

    const int B  = in_sizes[2];
    const int L1 = in_sizes[0] / (B * 2);
    const int L2 = in_sizes[1] / (B * 2);

    unsigned int* ws = (unsigned int*)d_ws;

    hipMemsetAsync(ws, 0, (size_t)B * sizeof(unsigned int), stream);

    const int Lmax = max(L1, L2);
    dim3 grid((Lmax + 63) / 64, B, 2);
    hipLaunchKernelGGL(hausdorff_directed_kernel, grid, dim3(256), 0, stream,
                       c1, c2, ws, L1, L2);

    hipLaunchKernelGGL(hausdorff_finalize_kernel, dim3(1), dim3(64), 0, stream,
                       ws, res, out, B);
}

// Round 3
// 35.657 us; speedup vs baseline: 2.0587x; 2.0587x over previous
//
#include <hip/hip_runtime.h>
#include <hip/hip_bf16.h>
#include <float.h>

#define EPSV 1e-6f
#define TILE 2048          // targets per LDS tile (float4 = 32 KB)
#define WAVES 8            // 512 threads
#define SPT 4              // src points per thread (per lane)
#define SRC_PER_BLOCK 256  // 64 lanes * SPT

// Directed Hausdorff (squared), expansion form:
//   |s'-t|^2 = |s'|^2 + (|t|^2 - 2 s'.t),   s' = s + eps
// Block: 512 threads = 8 waves. Block owns 256 src points (4 per lane; every
// wave's lane l holds the SAME 4 srcs). The 8 waves split each target tile
// 8 ways; each target is ONE broadcast ds_read_b128 amortized over 4 srcs.
// Cross-wave per-src min via LDS, block max, atomicMax(ws[b]).
// grid: x = ceil(Lmax/256), y = batch, z = direction.
__global__ __launch_bounds__(512, 2) void hausdorff_directed_kernel(
    const float* __restrict__ c1, const float* __restrict__ c2,
    unsigned int* __restrict__ ws, int L1, int L2) {

    const int b   = blockIdx.y;
    const int dir = blockIdx.z;

    const float* src; const float* tgt; int Lsrc, Ltgt;
    if (dir == 0) { src = c2 + (size_t)b * L2 * 2; tgt = c1 + (size_t)b * L1 * 2; Lsrc = L2; Ltgt = L1; }
    else          { src = c1 + (size_t)b * L1 * 2; tgt = c2 + (size_t)b * L2 * 2; Lsrc = L1; Ltgt = L2; }

    const int blockBase = blockIdx.x * SRC_PER_BLOCK;
    if (blockBase >= Lsrc) return;   // uniform across block

    const int lane = threadIdx.x & 63;
    const int w    = threadIdx.x >> 6;

    __shared__ float4 t_lds[TILE];
    __shared__ float  red[WAVES * SRC_PER_BLOCK];   // 8 KB
    __shared__ float  s2s[SRC_PER_BLOCK];           // 1 KB
    __shared__ float  red2[4];

    // Load this lane's 4 src points (same in every wave).
    float nsx[SPT], nsy[SPT], s2v[SPT];
    #pragma unroll
    for (int s = 0; s < SPT; ++s) {
        const int j = blockBase + s * 64 + lane;
        if (j < Lsrc) {
            float2 p = ((const float2*)src)[j];
            float sx = p.x + EPSV, sy = p.y + EPSV;
            nsx[s] = -2.0f * sx;
            nsy[s] = -2.0f * sy;
            s2v[s] = fmaf(sx, sx, sy * sy);
        } else {
            nsx[s] = 0.f; nsy[s] = 0.f;
            s2v[s] = -FLT_MAX;   // forces v <= 0 -> clamped to 0 (neutral for max)
        }
    }

    float mm[SPT];
    #pragma unroll
    for (int s = 0; s < SPT; ++s) mm[s] = FLT_MAX;

    for (int base = 0; base < Ltgt; base += TILE) {
        const int chunk = min(TILE, Ltgt - base);
        // cooperative, coalesced stage: (tx, ty, |t|^2, 0)
        for (int t = threadIdx.x; t < chunk; t += 512) {
            float2 p = ((const float2*)tgt)[base + t];
            t_lds[t] = make_float4(p.x, p.y, fmaf(p.x, p.x, p.y * p.y), 0.f);
        }
        __syncthreads();

        // wave w takes targets [w*256, min((w+1)*256, chunk))
        const int wbeg = w * (TILE / WAVES);
        const int wend = min(wbeg + TILE / WAVES, chunk);
        int i = wbeg;
        for (; i + 4 <= wend; i += 4) {
            float4 a0 = t_lds[i + 0];
            float4 a1 = t_lds[i + 1];
            float4 a2 = t_lds[i + 2];
            float4 a3 = t_lds[i + 3];
            #pragma unroll
            for (int s = 0; s < SPT; ++s) {
                float d0 = fmaf(a0.x, nsx[s], fmaf(a0.y, nsy[s], a0.z));
                float d1 = fmaf(a1.x, nsx[s], fmaf(a1.y, nsy[s], a1.z));
                float d2 = fmaf(a2.x, nsx[s], fmaf(a2.y, nsy[s], a2.z));
                float d3 = fmaf(a3.x, nsx[s], fmaf(a3.y, nsy[s], a3.z));
                mm[s] = fminf(mm[s], fminf(fminf(d0, d1), fminf(d2, d3)));
            }
        }
        for (; i < wend; ++i) {
            float4 a0 = t_lds[i];
            #pragma unroll
            for (int s = 0; s < SPT; ++s) {
                mm[s] = fminf(mm[s], fmaf(a0.x, nsx[s], fmaf(a0.y, nsy[s], a0.z)));
            }
        }
        __syncthreads();
    }

    // publish per-wave partial mins + (once) s2
    #pragma unroll
    for (int s = 0; s < SPT; ++s)
        red[w * SRC_PER_BLOCK + s * 64 + lane] = mm[s];
    if (w == 0) {
        #pragma unroll
        for (int s = 0; s < SPT; ++s)
            s2s[s * 64 + lane] = s2v[s];
    }
    __syncthreads();

    // combine: thread t < 256 owns src t
    const int t = threadIdx.x;
    float v = 0.0f;
    if (t < SRC_PER_BLOCK) {
        float m = red[t];
        #pragma unroll
        for (int ww = 1; ww < WAVES; ++ww)
            m = fminf(m, red[ww * SRC_PER_BLOCK + t]);
        v = fmaxf(s2s[t] + m, 0.0f);   // inactive srcs: s2 = -FLT_MAX -> clamped to 0
    }
    // max-reduce within each of the first 4 waves
    for (int off = 32; off > 0; off >>= 1)
        v = fmaxf(v, __shfl_down(v, off));
    if (t < SRC_PER_BLOCK && lane == 0) red2[t >> 6] = v;
    __syncthreads();
    if (t == 0) {
        float r = fmaxf(fmaxf(red2[0], red2[1]), fmaxf(red2[2], red2[3]));
        atomicMax(&ws[b], __float_as_uint(r));
    }
}

__global__ void hausdorff_finalize_kernel(const unsigned int* __restrict__ ws,
                                          const float* __restrict__ res,
                                          float* __restrict__ out, int B) {
    int t = threadIdx.x;
    if (t < B) {
        out[t] = sqrtf(__uint_as_float(ws[t])) * res[t];
    }
}

extern "C" void kernel_launch(void* const* d_in, const int* in_sizes, int n_in,
                              void* d_out, int out_size, void* d_ws, size_t ws_size,
                              hipStream_t stream) {
    const float* c1  = (const float*)d_in[0];
    const float* c2  = (const float*)d_in[1];
    const float* res = (const float*)d_in[2];
    float* out = (float*)d_out;

    const int B  = in_sizes[2];
    const int L1 = in_sizes[0] / (B * 2);
    const int L2 = in_sizes[1] / (B * 2);

    unsigned int* ws = (unsigned int*)d_ws;

    hipMemsetAsync(ws, 0, (size_t)B * sizeof(unsigned int), stream);

    const int Lmax = max(L1, L2);
    dim3 grid((Lmax + SRC_PER_BLOCK - 1) / SRC_PER_BLOCK, B, 2);
    hipLaunchKernelGGL(hausdorff_directed_kernel, grid, dim3(512), 0, stream,
                       c1, c2, ws, L1, L2);

    hipLaunchKernelGGL(hausdorff_finalize_kernel, dim3(1), dim3(64), 0, stream,
                       ws, res, out, B);
}

// Round 4
// 32.661 us; speedup vs baseline: 2.2476x; 1.0917x over previous
//
#include <hip/hip_runtime.h>
#include <hip/hip_bf16.h>
#include <float.h>

#define EPSV 1e-6f
#define MAXT 4096          // targets per LDS tile (float2 = 32 KB)
#define WAVES 8            // 512 threads
#define SPT 4              // src points per lane
#define SRC_PER_BLOCK 256  // 64 lanes * SPT

// Directed Hausdorff (squared), expansion form:
//   |s'-t|^2 = |s'|^2 + (|t|^2 - 2 s'.t),   s' = s + eps
// Block: 512 threads = 8 waves, owns 256 src points (4/lane; every wave's
// lane l holds the SAME 4 srcs). Waves split the target list 8 ways.
// Targets are read from LDS as float4 = TWO packed float2 points per
// ds_read_b128 (broadcast), |t|^2 computed on the VALU (amortized over 4
// srcs), min-tree fused via min3. Cross-wave per-src min via LDS, block
// max, atomicMax(ws[b]).
// grid: x = ceil(Lmax/256), y = batch, z = direction.
__global__ __launch_bounds__(512, 2) void hausdorff_directed_kernel(
    const float* __restrict__ c1, const float* __restrict__ c2,
    unsigned int* __restrict__ ws, int L1, int L2) {

    const int b   = blockIdx.y;
    const int dir = blockIdx.z;

    const float* src; const float* tgt; int Lsrc, Ltgt;
    if (dir == 0) { src = c2 + (size_t)b * L2 * 2; tgt = c1 + (size_t)b * L1 * 2; Lsrc = L2; Ltgt = L1; }
    else          { src = c1 + (size_t)b * L1 * 2; tgt = c2 + (size_t)b * L2 * 2; Lsrc = L1; Ltgt = L2; }

    const int blockBase = blockIdx.x * SRC_PER_BLOCK;
    if (blockBase >= Lsrc) return;   // uniform across block

    const int lane = threadIdx.x & 63;
    const int w    = threadIdx.x >> 6;

    __shared__ float4 t_lds[MAXT / 2];              // 32 KB, 2 targets per slot
    __shared__ float  red[WAVES * SRC_PER_BLOCK];   // 8 KB
    __shared__ float  s2s[SRC_PER_BLOCK];           // 1 KB
    __shared__ float  red2[4];

    // This lane's 4 src points (same in every wave).
    float nsx[SPT], nsy[SPT], s2v[SPT];
    #pragma unroll
    for (int s = 0; s < SPT; ++s) {
        const int j = blockBase + s * 64 + lane;
        if (j < Lsrc) {
            float2 p = ((const float2*)src)[j];
            float sx = p.x + EPSV, sy = p.y + EPSV;
            nsx[s] = -2.0f * sx;
            nsy[s] = -2.0f * sy;
            s2v[s] = fmaf(sx, sx, sy * sy);
        } else {
            nsx[s] = 0.f; nsy[s] = 0.f;
            s2v[s] = -FLT_MAX;   // forces v <= 0 -> clamped to 0 (neutral for max)
        }
    }

    float mm[SPT];
    #pragma unroll
    for (int s = 0; s < SPT; ++s) mm[s] = FLT_MAX;

    for (int base = 0; base < Ltgt; base += MAXT) {
        const int chunk = min(MAXT, Ltgt - base);
        const float2* tg = (const float2*)tgt + base;
        // cooperative, coalesced stage of raw float2 targets
        for (int t = threadIdx.x; t < chunk; t += 512) {
            ((float2*)t_lds)[t] = tg[t];
        }
        if (threadIdx.x == 0 && (chunk & 1)) {
            ((float2*)t_lds)[chunk] = tg[chunk - 1];   // dup pad (min-neutral)
        }
        __syncthreads();

        // wave w takes float4-pairs [w*P/8, (w+1)*P/8)
        const int P    = (chunk + 1) >> 1;
        const int pbeg = (w * P) >> 3;
        const int pend = ((w + 1) * P) >> 3;
        int i = pbeg;
        for (; i + 4 <= pend; i += 4) {
            float4 a0 = t_lds[i + 0];
            float4 a1 = t_lds[i + 1];
            float4 a2 = t_lds[i + 2];
            float4 a3 = t_lds[i + 3];
            float t2a0 = fmaf(a0.y, a0.y, a0.x * a0.x), t2b0 = fmaf(a0.w, a0.w, a0.z * a0.z);
            float t2a1 = fmaf(a1.y, a1.y, a1.x * a1.x), t2b1 = fmaf(a1.w, a1.w, a1.z * a1.z);
            float t2a2 = fmaf(a2.y, a2.y, a2.x * a2.x), t2b2 = fmaf(a2.w, a2.w, a2.z * a2.z);
            float t2a3 = fmaf(a3.y, a3.y, a3.x * a3.x), t2b3 = fmaf(a3.w, a3.w, a3.z * a3.z);
            #pragma unroll
            for (int s = 0; s < SPT; ++s) {
                float da0 = fmaf(a0.x, nsx[s], fmaf(a0.y, nsy[s], t2a0));
                float db0 = fmaf(a0.z, nsx[s], fmaf(a0.w, nsy[s], t2b0));
                mm[s] = fminf(fminf(mm[s], da0), db0);       // -> v_min3_f32
                float da1 = fmaf(a1.x, nsx[s], fmaf(a1.y, nsy[s], t2a1));
                float db1 = fmaf(a1.z, nsx[s], fmaf(a1.w, nsy[s], t2b1));
                mm[s] = fminf(fminf(mm[s], da1), db1);
                float da2 = fmaf(a2.x, nsx[s], fmaf(a2.y, nsy[s], t2a2));
                float db2 = fmaf(a2.z, nsx[s], fmaf(a2.w, nsy[s], t2b2));
                mm[s] = fminf(fminf(mm[s], da2), db2);
                float da3 = fmaf(a3.x, nsx[s], fmaf(a3.y, nsy[s], t2a3));
                float db3 = fmaf(a3.z, nsx[s], fmaf(a3.w, nsy[s], t2b3));
                mm[s] = fminf(fminf(mm[s], da3), db3);
            }
        }
        for (; i < pend; ++i) {
            float4 a0 = t_lds[i];
            float t2a0 = fmaf(a0.y, a0.y, a0.x * a0.x), t2b0 = fmaf(a0.w, a0.w, a0.z * a0.z);
            #pragma unroll
            for (int s = 0; s < SPT; ++s) {
                float da0 = fmaf(a0.x, nsx[s], fmaf(a0.y, nsy[s], t2a0));
                float db0 = fmaf(a0.z, nsx[s], fmaf(a0.w, nsy[s], t2b0));
                mm[s] = fminf(fminf(mm[s], da0), db0);
            }
        }
        __syncthreads();
    }

    // publish per-wave partial mins + (once) s2
    #pragma unroll
    for (int s = 0; s < SPT; ++s)
        red[w * SRC_PER_BLOCK + s * 64 + lane] = mm[s];
    if (w == 0) {
        #pragma unroll
        for (int s = 0; s < SPT; ++s)
            s2s[s * 64 + lane] = s2v[s];
    }
    __syncthreads();

    // combine: thread t < 256 owns src t
    const int t = threadIdx.x;
    float v = 0.0f;
    if (t < SRC_PER_BLOCK) {
        float m = red[t];
        #pragma unroll
        for (int ww = 1; ww < WAVES; ++ww)
            m = fminf(m, red[ww * SRC_PER_BLOCK + t]);
        v = fmaxf(s2s[t] + m, 0.0f);   // inactive srcs: s2 = -FLT_MAX -> clamped to 0
    }
    for (int off = 32; off > 0; off >>= 1)
        v = fmaxf(v, __shfl_down(v, off));
    if (t < SRC_PER_BLOCK && lane == 0) red2[t >> 6] = v;
    __syncthreads();
    if (t == 0) {
        float r = fmaxf(fmaxf(red2[0], red2[1]), fmaxf(red2[2], red2[3]));
        atomicMax(&ws[b], __float_as_uint(r));
    }
}

__global__ void hausdorff_finalize_kernel(const unsigned int* __restrict__ ws,
                                          const float* __restrict__ res,
                                          float* __restrict__ out, int B) {
    int t = threadIdx.x;
    if (t < B) {
        out[t] = sqrtf(__uint_as_float(ws[t])) * res[t];
    }
}

extern "C" void kernel_launch(void* const* d_in, const int* in_sizes, int n_in,
                              void* d_out, int out_size, void* d_ws, size_t ws_size,
                              hipStream_t stream) {
    const float* c1  = (const float*)d_in[0];
    const float* c2  = (const float*)d_in[1];
    const float* res = (const float*)d_in[2];
    float* out = (float*)d_out;

    const int B  = in_sizes[2];
    const int L1 = in_sizes[0] / (B * 2);
    const int L2 = in_sizes[1] / (B * 2);

    unsigned int* ws = (unsigned int*)d_ws;

    hipMemsetAsync(ws, 0, (size_t)B * sizeof(unsigned int), stream);

    const int Lmax = max(L1, L2);
    dim3 grid((Lmax + SRC_PER_BLOCK - 1) / SRC_PER_BLOCK, B, 2);
    hipLaunchKernelGGL(hausdorff_directed_kernel, grid, dim3(512), 0, stream,
                       c1, c2, ws, L1, L2);

    hipLaunchKernelGGL(hausdorff_finalize_kernel, dim3(1), dim3(64), 0, stream,
                       ws, res, out, B);
}